// Round 1
// baseline (1705.939 us; speedup 1.0000x reference)
//
#include <hip/hip_runtime.h>
#include <math.h>

// Problem constants (match reference setup_inputs)
#define Bz   4096
#define Tz   200
#define Fz   18
#define Uz   128
#define NIDS 1000
#define NCH  4     // chains per workgroup; 1000/4 = 250 workgroups

__device__ __forceinline__ float hsig(float x) {
    return fminf(fmaxf(fmaf(x, 0.2f, 0.5f), 0.0f), 1.0f);
}

// ---------------------------------------------------------------------------
// K1: winner per (t,id): win[t*NIDS+id] = max{b : ids[b,t]==id}  (last-wins)
// ---------------------------------------------------------------------------
__global__ void k_winner(const float* __restrict__ in, int* __restrict__ win) {
    int idx = blockIdx.x * blockDim.x + threadIdx.x;   // idx = b*T + t
    if (idx >= Bz * Tz) return;
    int b = idx / Tz;
    int t = idx - b * Tz;
    int id = (int)in[(size_t)idx * Fz];                // col 0 holds float-encoded id
    id = min(max(id, 0), NIDS - 1);
    atomicMax(&win[t * NIDS + id], b);
}

// ---------------------------------------------------------------------------
// One GRU step for NCH chains. Weights in registers, state in LDS.
// Thread mapping: c1 = tid (stage1 col 0..255: z cols 0..127, r cols 128..255)
//                 kh = tid&1, c2 = tid>>1 (stage2 col 0..127, k-half split)
// a0..a3 >= 0 means chain j is active (its h gets written).
// ---------------------------------------------------------------------------
__device__ __forceinline__ void gru_step(
    const float* __restrict__ wzr, const float* __restrict__ wh,
    const float* __restrict__ wk1, const float* __restrict__ wk2,
    float bZR, float bH,
    float* hlds, float* ubuf, float* zbuf, const float* xlds,
    int tid, int a0, int a1, int a2, int a3)
{
    const int c1 = tid;
    const int kh = tid & 1;
    const int c2 = tid >> 1;

    // ---- stage 1: mx (x@kernel), mh (h@Rzr), gates z/r, u = r*h ----
    float az[NCH], am2[NCH];
#pragma unroll
    for (int j = 0; j < NCH; ++j) { az[j] = bZR; am2[j] = bH; }

    const float4* x4 = (const float4*)xlds;            // [NCH][20] padded rows
#pragma unroll
    for (int q = 0; q < 4; ++q) {
#pragma unroll
        for (int j = 0; j < NCH; ++j) {
            float4 xv = x4[j * 5 + q];
            az[j]  = fmaf(xv.x, wk1[4*q+0], az[j]);
            az[j]  = fmaf(xv.y, wk1[4*q+1], az[j]);
            az[j]  = fmaf(xv.z, wk1[4*q+2], az[j]);
            az[j]  = fmaf(xv.w, wk1[4*q+3], az[j]);
            am2[j] = fmaf(xv.x, wk2[4*q+0], am2[j]);
            am2[j] = fmaf(xv.y, wk2[4*q+1], am2[j]);
            am2[j] = fmaf(xv.z, wk2[4*q+2], am2[j]);
            am2[j] = fmaf(xv.w, wk2[4*q+3], am2[j]);
        }
    }
#pragma unroll
    for (int j = 0; j < NCH; ++j) {
        float x16 = xlds[j*20 + 16], x17 = xlds[j*20 + 17];
        az[j]  = fmaf(x16, wk1[16], az[j]);
        az[j]  = fmaf(x17, wk1[17], az[j]);
        am2[j] = fmaf(x16, wk2[16], am2[j]);
        am2[j] = fmaf(x17, wk2[17], am2[j]);
    }

    const float4* h4 = (const float4*)hlds;            // [NCH][128]
#pragma unroll
    for (int q = 0; q < 32; ++q) {
#pragma unroll
        for (int j = 0; j < NCH; ++j) {
            float4 hv = h4[j * 32 + q];
            az[j] = fmaf(hv.x, wzr[4*q+0], az[j]);
            az[j] = fmaf(hv.y, wzr[4*q+1], az[j]);
            az[j] = fmaf(hv.z, wzr[4*q+2], az[j]);
            az[j] = fmaf(hv.w, wzr[4*q+3], az[j]);
        }
    }

    if (c1 < Uz) {                                     // z half (waves 0,1)
#pragma unroll
        for (int j = 0; j < NCH; ++j) zbuf[j*Uz + c1] = hsig(az[j]);
    } else {                                           // r half (waves 2,3)
        int cc = c1 - Uz;
#pragma unroll
        for (int j = 0; j < NCH; ++j) {
            float r = hsig(az[j]);
            ubuf[j*Uz + cc] = r * hlds[j*Uz + cc];
        }
    }
    __syncthreads();

    // ---- stage 2: hh = tanh(mx2 + u@Rh), h_new = z*h + (1-z)*hh ----
    float p[NCH];
#pragma unroll
    for (int j = 0; j < NCH; ++j) p[j] = 0.0f;
    const float4* u4 = (const float4*)ubuf;
#pragma unroll
    for (int q = 0; q < 16; ++q) {
#pragma unroll
        for (int j = 0; j < NCH; ++j) {
            float4 uv = u4[j * 32 + kh * 16 + q];
            p[j] = fmaf(uv.x, wh[4*q+0], p[j]);
            p[j] = fmaf(uv.y, wh[4*q+1], p[j]);
            p[j] = fmaf(uv.z, wh[4*q+2], p[j]);
            p[j] = fmaf(uv.w, wh[4*q+3], p[j]);
        }
    }
#pragma unroll
    for (int j = 0; j < NCH; ++j) p[j] += __shfl_xor(p[j], 1, 64);

    if (kh == 0) {
        int act[NCH] = {a0, a1, a2, a3};
#pragma unroll
        for (int j = 0; j < NCH; ++j) {
            float hh = tanhf(am2[j] + p[j]);
            float z  = zbuf[j*Uz + c2];
            float ho = hlds[j*Uz + c2];
            float hn = fmaf(z, ho - hh, hh);           // z*ho + (1-z)*hh
            if (act[j] >= 0) hlds[j*Uz + c2] = hn;
        }
    }
}

// ---------------------------------------------------------------------------
// K2: advance all 1000 independent id-chains through t = 0..198.
// ---------------------------------------------------------------------------
__global__ __launch_bounds__(256, 1) void k_scan(
    const float* __restrict__ in,  const float* __restrict__ ker,
    const float* __restrict__ rk,  const float* __restrict__ bias,
    const float* __restrict__ sh0, const int* __restrict__ win,
    float* __restrict__ sfinal)
{
    const int tid = threadIdx.x;
    const int bx  = blockIdx.x;
    const int k0  = bx * NCH;
    const int c1  = tid;
    const int kh  = tid & 1;
    const int c2  = tid >> 1;

    __shared__ __align__(16) float hlds[NCH*Uz];
    __shared__ __align__(16) float ubuf[NCH*Uz];
    __shared__ __align__(16) float zbuf[NCH*Uz];
    __shared__ __align__(16) float xlds[NCH*20];

    // Persistent weights in registers (~230 VGPR)
    float wzr[Uz];
#pragma unroll
    for (int k = 0; k < Uz; ++k) wzr[k] = rk[k*384 + c1];
    float wh[64];
#pragma unroll
    for (int k = 0; k < 64; ++k) wh[k] = rk[(kh*64 + k)*384 + 256 + c2];
    float wk1[Fz], wk2[Fz];
#pragma unroll
    for (int e = 0; e < Fz; ++e) {
        wk1[e] = ker[e*384 + c1];
        wk2[e] = ker[e*384 + 256 + c2];
    }
    const float bZR = bias[c1];
    const float bH  = bias[256 + c2];

    // init h from shared0 (chains k0..k0+3 are contiguous rows)
    for (int idx = tid; idx < NCH*Uz; idx += 256) hlds[idx] = sh0[k0*Uz + idx];

    const int4* winp = (const int4*)win;               // element t*250 + bx
    int4 wv_cur = winp[0*250 + bx];
    int4 wv_nxt = winp[1*250 + bx];

    int xj = 0, xe = 0;
    if (tid < NCH*Fz) { xj = tid / Fz; xe = tid - xj*Fz; }

    if (tid < NCH*Fz) {                                // x(0)
        int wvj = (xj==0) ? wv_cur.x : (xj==1) ? wv_cur.y : (xj==2) ? wv_cur.z : wv_cur.w;
        xlds[xj*20 + xe] = (wvj >= 0) ? in[((size_t)wvj*Tz + 0)*Fz + xe] : 0.0f;
    }
    __syncthreads();

    for (int t = 0; t < Tz - 1; ++t) {
        // prefetch win(t+2) and x(t+1)
        int tf = t + 2; if (tf > Tz - 1) tf = Tz - 1;
        int4 wv_fut = winp[tf*250 + bx];
        float xrN = 0.0f;
        if (tid < NCH*Fz) {
            int wvj = (xj==0) ? wv_nxt.x : (xj==1) ? wv_nxt.y : (xj==2) ? wv_nxt.z : wv_nxt.w;
            if (wvj >= 0) xrN = in[((size_t)wvj*Tz + (t+1))*Fz + xe];
        }

        gru_step(wzr, wh, wk1, wk2, bZR, bH, hlds, ubuf, zbuf, xlds,
                 tid, wv_cur.x, wv_cur.y, wv_cur.z, wv_cur.w);

        if (tid < NCH*Fz) xlds[xj*20 + xe] = xrN;      // stage x(t+1)
        __syncthreads();

        wv_cur = wv_nxt;
        wv_nxt = wv_fut;
    }

    for (int idx = tid; idx < NCH*Uz; idx += 256) sfinal[k0*Uz + idx] = hlds[idx];
}

// ---------------------------------------------------------------------------
// K3: final step t=199 for ALL 4096 rows + fused MLP head -> d_out[4096]
// ---------------------------------------------------------------------------
__global__ __launch_bounds__(256, 1) void k_final(
    const float* __restrict__ in,  const float* __restrict__ ker,
    const float* __restrict__ rk,  const float* __restrict__ bias,
    const float* __restrict__ sfinal,
    const float* __restrict__ w1,  const float* __restrict__ b1,
    const float* __restrict__ w2,  const float* __restrict__ b2,
    float* __restrict__ out)
{
    const int tid = threadIdx.x;
    const int c1  = tid;
    const int kh  = tid & 1;
    const int c2  = tid >> 1;

    __shared__ __align__(16) float hlds[NCH*Uz];
    __shared__ __align__(16) float ubuf[NCH*Uz];
    __shared__ __align__(16) float zbuf[NCH*Uz];
    __shared__ __align__(16) float xlds[NCH*20];

    float wzr[Uz];
#pragma unroll
    for (int k = 0; k < Uz; ++k) wzr[k] = rk[k*384 + c1];
    float wh[64];
#pragma unroll
    for (int k = 0; k < 64; ++k) wh[k] = rk[(kh*64 + k)*384 + 256 + c2];
    float wk1[Fz], wk2[Fz];
#pragma unroll
    for (int e = 0; e < Fz; ++e) {
        wk1[e] = ker[e*384 + c1];
        wk2[e] = ker[e*384 + 256 + c2];
    }
    const float bZR = bias[c1];
    const float bH  = bias[256 + c2];

    for (int it = 0; it < 4; ++it) {
        int bbase = blockIdx.x * 16 + it * 4;

        int idj[NCH];
#pragma unroll
        for (int j = 0; j < NCH; ++j) {
            int id = (int)in[((size_t)(bbase + j)*Tz + (Tz - 1))*Fz];
            idj[j] = min(max(id, 0), NIDS - 1);
        }
        for (int idx = tid; idx < NCH*Uz; idx += 256) {
            int j = idx >> 7, c = idx & 127;
            int id = (j==0) ? idj[0] : (j==1) ? idj[1] : (j==2) ? idj[2] : idj[3];
            hlds[idx] = sfinal[id*Uz + c];
        }
        if (tid < NCH*Fz) {
            int j = tid / Fz, e = tid - j*Fz;
            xlds[j*20 + e] = in[((size_t)(bbase + j)*Tz + (Tz - 1))*Fz + e];
        }
        __syncthreads();

        gru_step(wzr, wh, wk1, wk2, bZR, bH, hlds, ubuf, zbuf, xlds,
                 tid, 0, 0, 0, 0 /* all active */);
        __syncthreads();                                // h_new visible in hlds

        // MLP head: out = sigmoid(relu(h@w1+b1)@w2 + b2); j = wave index
        {
            int j    = tid >> 6;
            int lane = tid & 63;
            float dacc = b1[lane];
#pragma unroll
            for (int k = 0; k < Uz; ++k)
                dacc = fmaf(hlds[j*Uz + k], w1[k*64 + lane], dacc);
            float v = fmaxf(dacc, 0.0f) * w2[lane];
#pragma unroll
            for (int off = 32; off > 0; off >>= 1) v += __shfl_xor(v, off, 64);
            if (lane == 0)
                out[bbase + j] = 1.0f / (1.0f + expf(-(v + b2[0])));
        }
        __syncthreads();                                // before next iter reuses LDS
    }
}

// ---------------------------------------------------------------------------
extern "C" void kernel_launch(void* const* d_in, const int* in_sizes, int n_in,
                              void* d_out, int out_size, void* d_ws, size_t ws_size,
                              hipStream_t stream) {
    const float* in   = (const float*)d_in[0];
    const float* ker  = (const float*)d_in[1];
    const float* rk   = (const float*)d_in[2];
    const float* bias = (const float*)d_in[3];
    const float* sh0  = (const float*)d_in[4];
    const float* w1   = (const float*)d_in[5];
    const float* b1   = (const float*)d_in[6];
    const float* w2   = (const float*)d_in[7];
    const float* b2   = (const float*)d_in[8];
    float* out = (float*)d_out;

    int*   win    = (int*)d_ws;                                         // [T][NIDS]
    float* sfinal = (float*)((char*)d_ws + (size_t)Tz*NIDS*sizeof(int)); // [NIDS][U]

    hipMemsetAsync(win, 0xFF, (size_t)Tz*NIDS*sizeof(int), stream);     // -1

    hipLaunchKernelGGL(k_winner, dim3((Bz*Tz + 255)/256), dim3(256), 0, stream,
                       in, win);
    hipLaunchKernelGGL(k_scan, dim3(NIDS/NCH), dim3(256), 0, stream,
                       in, ker, rk, bias, sh0, win, sfinal);
    hipLaunchKernelGGL(k_final, dim3(Bz/16), dim3(256), 0, stream,
                       in, ker, rk, bias, sfinal, w1, b1, w2, b2, out);
}

// Round 3
// 1490.179 us; speedup vs baseline: 1.1448x; 1.1448x over previous
//
#include <hip/hip_runtime.h>
#include <math.h>

#define Bz   4096
#define Tz   200
#define Fz   18
#define Uz   128
#define NIDS 1000
#define NCH  4
#define NWG  250   // NIDS/NCH

__device__ __forceinline__ float hsig(float x) {
    return fminf(fmaxf(fmaf(x, 0.2f, 0.5f), 0.0f), 1.0f);
}
// wave-uniform broadcast: VGPR lane -> SGPR (VALU pipe, not LDS pipe)
__device__ __forceinline__ float rlane(float v, int l) {
    return __int_as_float(__builtin_amdgcn_readlane(__float_as_int(v), l));
}

// ---------------------------------------------------------------------------
// K1: winner per (t,id): win[t*NIDS+id] = max{b : ids[b,t]==id}  (last-wins)
// ---------------------------------------------------------------------------
__global__ void k_winner(const float* __restrict__ in, int* __restrict__ win) {
    int idx = blockIdx.x * blockDim.x + threadIdx.x;   // idx = b*T + t
    if (idx >= Bz * Tz) return;
    int b = idx / Tz;
    int t = idx - b * Tz;
    int id = (int)in[(size_t)idx * Fz];
    id = min(max(id, 0), NIDS - 1);
    atomicMax(&win[t * NIDS + id], b);
}

// ---------------------------------------------------------------------------
// One GRU step, 512-thread layout, FMAs fed from registers via readlane.
//   stage1: column c1 = tid&255 (z:0..127, r:128..255), k-half kh = tid>>8
//   stage2: column c2 = tid&127, k-quarter kq = tid>>7
//   hd[j]  = h[j][kh*64 + lane]   (readlane source for stage1)
//   xd     = x[lane/9][kh*9 + lane%9]  (lanes 0..35; readlane source)
//   xd2    = x[lane/9][(kq&1)*9 + lane%9] (stage2 x source, kq<2)
// ---------------------------------------------------------------------------
template<bool WRITE_ALL>
__device__ __forceinline__ void step512(
    int tid, int lane, int c1, int kh, int c2, int kq,
    const float* wzr, const float* wh, const float* wk1, const float* wk2,
    float bZR, float bH, int4 act,
    const float* hd, float xd, float xd2,
    float* hlds, float* ubuf, float* zbuf,
    float4* pbuf1, float4 (*pbuf2)[Uz])
{
    // ---- stage 1 partial: az[j] over this thread's k-half + x-features ----
    float az[NCH];
#pragma unroll
    for (int j = 0; j < NCH; ++j) az[j] = bZR;
#pragma unroll
    for (int kl = 0; kl < 64; ++kl) {
        float w = wzr[kl];
#pragma unroll
        for (int j = 0; j < NCH; ++j)
            az[j] = fmaf(rlane(hd[j], kl), w, az[j]);
    }
#pragma unroll
    for (int e = 0; e < 9; ++e) {
        float w = wk1[e];
#pragma unroll
        for (int j = 0; j < NCH; ++j)
            az[j] = fmaf(rlane(xd, j * 9 + e), w, az[j]);
    }
    if (kh == 1) pbuf1[c1] = make_float4(az[0], az[1], az[2], az[3]);
    __syncthreads();                                   // A
    if (kh == 0) {
        float4 o = pbuf1[c1];
        az[0] += o.x; az[1] += o.y; az[2] += o.z; az[3] += o.w;
        if (c1 < Uz) {
#pragma unroll
            for (int j = 0; j < NCH; ++j) zbuf[j * Uz + c1] = hsig(az[j]);
        } else {
            int cc = c1 - Uz;
#pragma unroll
            for (int j = 0; j < NCH; ++j)
                ubuf[j * Uz + cc] = hsig(az[j]) * hlds[j * Uz + cc];
        }
    }
    __syncthreads();                                   // B
    // ---- stage 2: p[j] partial over this thread's k-quarter of u @ Rh ----
    float ud[NCH];
#pragma unroll
    for (int j = 0; j < NCH; ++j) ud[j] = ubuf[j * Uz + kq * 32 + (lane & 31)];
    float p[NCH];
#pragma unroll
    for (int j = 0; j < NCH; ++j) p[j] = bH;
#pragma unroll
    for (int kl = 0; kl < 32; ++kl) {
        float w = wh[kl];
#pragma unroll
        for (int j = 0; j < NCH; ++j)
            p[j] = fmaf(rlane(ud[j], kl), w, p[j]);
    }
    if (kq < 2) {
#pragma unroll
        for (int e = 0; e < 9; ++e) {
            float w = wk2[e];
#pragma unroll
            for (int j = 0; j < NCH; ++j)
                p[j] = fmaf(rlane(xd2, j * 9 + e), w, p[j]);
        }
    }
    pbuf2[kq][c2] = make_float4(p[0], p[1], p[2], p[3]);
    __syncthreads();                                   // C
    if (tid < Uz) {
        float4 a = pbuf2[0][tid], b = pbuf2[1][tid];
        float4 c = pbuf2[2][tid], d = pbuf2[3][tid];
        float m2[NCH] = {a.x + b.x + c.x + d.x, a.y + b.y + c.y + d.y,
                         a.z + b.z + c.z + d.z, a.w + b.w + c.w + d.w};
        int av[NCH] = {act.x, act.y, act.z, act.w};
#pragma unroll
        for (int j = 0; j < NCH; ++j) {
            float hh = tanhf(m2[j]);
            float z  = zbuf[j * Uz + tid];
            float ho = hlds[j * Uz + tid];
            float hn = fmaf(z, ho - hh, hh);
            if (WRITE_ALL || av[j] >= 0) hlds[j * Uz + tid] = hn;
        }
    }
    __syncthreads();                                   // D
}

// ---------------------------------------------------------------------------
// K2: 250 wgs x 512 threads; 4 chains per wg; t = 0..198
// ---------------------------------------------------------------------------
__global__ __launch_bounds__(512)
__attribute__((amdgpu_waves_per_eu(2, 2)))
void k_scan(const float* __restrict__ in,  const float* __restrict__ ker,
            const float* __restrict__ rk,  const float* __restrict__ bias,
            const float* __restrict__ sh0, const int* __restrict__ win,
            float* __restrict__ sfinal)
{
    const int tid  = threadIdx.x;
    const int lane = tid & 63;
    const int c1   = tid & 255;
    const int kh   = tid >> 8;
    const int c2   = tid & 127;
    const int kq   = tid >> 7;
    const int bx   = blockIdx.x;

    __shared__ float hlds[NCH * Uz];
    __shared__ float ubuf[NCH * Uz];
    __shared__ float zbuf[NCH * Uz];
    __shared__ __align__(16) float4 pbuf1[256];
    __shared__ __align__(16) float4 pbuf2[4][Uz];

    // ---- persistent weights in registers (~115 floats/thread) ----
    float wzr[64];
#pragma unroll
    for (int k = 0; k < 64; ++k) wzr[k] = rk[(kh * 64 + k) * 384 + c1];
    float wh[32];
#pragma unroll
    for (int k = 0; k < 32; ++k) wh[k] = rk[(kq * 32 + k) * 384 + 256 + c2];
    float wk1[9];
#pragma unroll
    for (int e = 0; e < 9; ++e) wk1[e] = ker[(kh * 9 + e) * 384 + c1];
    float wk2[9];
    {
        int kq2 = kq & 1;
#pragma unroll
        for (int e = 0; e < 9; ++e) wk2[e] = ker[(kq2 * 9 + e) * 384 + 256 + c2];
    }
    const float bZR = (kh == 0) ? bias[c1] : 0.0f;
    const float bH  = (kq == 0) ? bias[256 + c2] : 0.0f;

    // x-gather mapping (lanes 0..35 hold 4 chains x 9 features)
    const int  xj   = lane / 9;
    const int  xe   = lane - xj * 9;
    const bool xact = (lane < 36);
    const int  f1   = kh * 9 + xe;
    const int  f2   = (kq & 1) * 9 + xe;

    auto gx = [&](int4 wv, int t, int f) -> float {
        if (!xact) return 0.0f;
        int w = (xj == 0) ? wv.x : (xj == 1) ? wv.y : (xj == 2) ? wv.z : wv.w;
        if (w < 0) return 0.0f;
        return in[((size_t)w * Tz + t) * Fz + f];
    };

    for (int i = tid; i < NCH * Uz; i += 512) hlds[i] = sh0[bx * NCH * Uz + i];

    const int4* winp = (const int4*)win;               // [Tz][NWG]
    int4 wv_cur = winp[0 * NWG + bx];
    int4 wv_nxt = winp[1 * NWG + bx];
    float xd  = gx(wv_cur, 0, f1);
    float xd2 = gx(wv_cur, 0, f2);
    __syncthreads();
    float hd[NCH];
#pragma unroll
    for (int j = 0; j < NCH; ++j) hd[j] = hlds[j * Uz + kh * 64 + lane];

    for (int t = 0; t < Tz - 1; ++t) {
        int tf = (t + 2 < Tz) ? t + 2 : Tz - 1;
        int4  wv_fut = winp[tf * NWG + bx];
        float xdN  = gx(wv_nxt, t + 1, f1);            // prefetch x(t+1)
        float xd2N = gx(wv_nxt, t + 1, f2);

        step512<false>(tid, lane, c1, kh, c2, kq, wzr, wh, wk1, wk2,
                       bZR, bH, wv_cur, hd, xd, xd2,
                       hlds, ubuf, zbuf, pbuf1, pbuf2);

#pragma unroll
        for (int j = 0; j < NCH; ++j) hd[j] = hlds[j * Uz + kh * 64 + lane];
        xd = xdN; xd2 = xd2N;
        wv_cur = wv_nxt; wv_nxt = wv_fut;
    }

    for (int i = tid; i < NCH * Uz; i += 512) sfinal[bx * NCH * Uz + i] = hlds[i];
}

// ---------------------------------------------------------------------------
// K3: final step t=199 for all 4096 rows + fused MLP head
// 256 wgs x 512 threads, 4 iterations of 4 rows
// ---------------------------------------------------------------------------
__global__ __launch_bounds__(512)
__attribute__((amdgpu_waves_per_eu(2, 2)))
void k_final(const float* __restrict__ in,  const float* __restrict__ ker,
             const float* __restrict__ rk,  const float* __restrict__ bias,
             const float* __restrict__ sfinal,
             const float* __restrict__ w1,  const float* __restrict__ b1,
             const float* __restrict__ w2,  const float* __restrict__ b2,
             float* __restrict__ out)
{
    const int tid  = threadIdx.x;
    const int lane = tid & 63;
    const int c1   = tid & 255;
    const int kh   = tid >> 8;
    const int c2   = tid & 127;
    const int kq   = tid >> 7;

    __shared__ float hlds[NCH * Uz];
    __shared__ float ubuf[NCH * Uz];
    __shared__ float zbuf[NCH * Uz];
    __shared__ __align__(16) float4 pbuf1[256];
    __shared__ __align__(16) float4 pbuf2[4][Uz];

    float wzr[64];
#pragma unroll
    for (int k = 0; k < 64; ++k) wzr[k] = rk[(kh * 64 + k) * 384 + c1];
    float wh[32];
#pragma unroll
    for (int k = 0; k < 32; ++k) wh[k] = rk[(kq * 32 + k) * 384 + 256 + c2];
    float wk1[9];
#pragma unroll
    for (int e = 0; e < 9; ++e) wk1[e] = ker[(kh * 9 + e) * 384 + c1];
    float wk2[9];
    {
        int kq2 = kq & 1;
#pragma unroll
        for (int e = 0; e < 9; ++e) wk2[e] = ker[(kq2 * 9 + e) * 384 + 256 + c2];
    }
    const float bZR = (kh == 0) ? bias[c1] : 0.0f;
    const float bH  = (kq == 0) ? bias[256 + c2] : 0.0f;

    const int  xj   = lane / 9;
    const int  xe   = lane - xj * 9;
    const bool xact = (lane < 36);
    const int  f1   = kh * 9 + xe;
    const int  f2   = (kq & 1) * 9 + xe;

    for (int it = 0; it < 4; ++it) {
        int bbase = blockIdx.x * 16 + it * 4;

        {   // gather h = sfinal[id] ; tid = j*128 + c
            int j  = tid >> 7, c = tid & 127;
            int id = (int)in[((size_t)(bbase + j) * Tz + (Tz - 1)) * Fz];
            id = min(max(id, 0), NIDS - 1);
            hlds[tid] = sfinal[id * Uz + c];
        }
        float xd = 0.0f, xd2 = 0.0f;
        if (xact) {
            xd  = in[((size_t)(bbase + xj) * Tz + (Tz - 1)) * Fz + f1];
            xd2 = in[((size_t)(bbase + xj) * Tz + (Tz - 1)) * Fz + f2];
        }
        __syncthreads();
        float hd[NCH];
#pragma unroll
        for (int j = 0; j < NCH; ++j) hd[j] = hlds[j * Uz + kh * 64 + lane];

        step512<true>(tid, lane, c1, kh, c2, kq, wzr, wh, wk1, wk2,
                      bZR, bH, make_int4(0, 0, 0, 0), hd, xd, xd2,
                      hlds, ubuf, zbuf, pbuf1, pbuf2);

        // MLP head: wave j (tid<256) handles row j; lane = hidden unit
        if (tid < 256) {
            int j  = tid >> 6;
            int un = tid & 63;
            float dacc = b1[un];
#pragma unroll
            for (int k = 0; k < Uz; ++k)
                dacc = fmaf(hlds[j * Uz + k], w1[k * 64 + un], dacc);
            float v = fmaxf(dacc, 0.0f) * w2[un];
#pragma unroll
            for (int off = 32; off > 0; off >>= 1) v += __shfl_xor(v, off, 64);
            if (un == 0)
                out[bbase + j] = 1.0f / (1.0f + expf(-(v + b2[0])));
        }
        __syncthreads();
    }
}

// ---------------------------------------------------------------------------
extern "C" void kernel_launch(void* const* d_in, const int* in_sizes, int n_in,
                              void* d_out, int out_size, void* d_ws, size_t ws_size,
                              hipStream_t stream) {
    const float* in   = (const float*)d_in[0];
    const float* ker  = (const float*)d_in[1];
    const float* rk   = (const float*)d_in[2];
    const float* bias = (const float*)d_in[3];
    const float* sh0  = (const float*)d_in[4];
    const float* w1   = (const float*)d_in[5];
    const float* b1   = (const float*)d_in[6];
    const float* w2   = (const float*)d_in[7];
    const float* b2   = (const float*)d_in[8];
    float* out = (float*)d_out;

    int*   win    = (int*)d_ws;                                          // [Tz][NIDS]
    float* sfinal = (float*)((char*)d_ws + (size_t)Tz * NIDS * sizeof(int));

    hipMemsetAsync(win, 0xFF, (size_t)Tz * NIDS * sizeof(int), stream);  // -1

    hipLaunchKernelGGL(k_winner, dim3((Bz * Tz + 255) / 256), dim3(256), 0, stream,
                       in, win);
    hipLaunchKernelGGL(k_scan, dim3(NWG), dim3(512), 0, stream,
                       in, ker, rk, bias, sh0, win, sfinal);
    hipLaunchKernelGGL(k_final, dim3(Bz / 16), dim3(512), 0, stream,
                       in, ker, rk, bias, sfinal, w1, b1, w2, b2, out);
}

// Round 4
// 1205.722 us; speedup vs baseline: 1.4149x; 1.2359x over previous
//
#include <hip/hip_runtime.h>
#include <math.h>

#define Bz   4096
#define Tz   200
#define Fz   18
#define Uz   128
#define NIDS 1000
#define NCH  4
#define NWG  250   // NIDS/NCH

__device__ __forceinline__ float hsig(float x) {
    return fminf(fmaxf(fmaf(x, 0.2f, 0.5f), 0.0f), 1.0f);
}
__device__ __forceinline__ float rlane(float v, int l) {
    return __int_as_float(__builtin_amdgcn_readlane(__float_as_int(v), l));
}

// ---------------------------------------------------------------------------
// K1: winner per (t,id): win[t*NIDS+id] = max{b : ids[b,t]==id}  (last-wins)
// ---------------------------------------------------------------------------
__global__ void k_winner(const float* __restrict__ in, int* __restrict__ win) {
    int idx = blockIdx.x * blockDim.x + threadIdx.x;
    if (idx >= Bz * Tz) return;
    int b = idx / Tz, t = idx - b * Tz;
    int id = (int)in[(size_t)idx * Fz];
    id = min(max(id, 0), NIDS - 1);
    atomicMax(&win[t * NIDS + id], b);
}

// ---------------------------------------------------------------------------
// One GRU step. 512 threads = 8 waves. Wave w owns k-range [16w, 16w+16).
// stage1: lane handles cols {lane, lane+64, lane+128, lane+192} of 256 (M=4)
// stage2: lane handles cols {lane, lane+64} of 128 (M=2)
// All LDS state j-packed float4 (j = chain 0..3). All readlane idx uniform.
// ---------------------------------------------------------------------------
template<bool MASK>
__device__ __forceinline__ void gstep(
    int tid, int w, int lane, int l15,
    const float (&wzr)[16][4], const float (&wh)[16][2],
    const float (&wk1)[3][4], const float (&wk2)[3][2],
    int f0, int f1, int f2,
    float breg, float breg2,
    float4* hlds, float4* ubuf, float4* zbuf, float4* p1, float4* p2,
    float xa, float xb, int4 act)
{
    // ---- stage 1: partials of [x@K + h@Rzr] over this wave's k/f slice ----
    float4 hd4 = hlds[w * 16 + l15];
    float hdj[4] = {hd4.x, hd4.y, hd4.z, hd4.w};
    float az[4][4];
#pragma unroll
    for (int i = 0; i < 4; ++i) { az[i][0]=0.f; az[i][1]=0.f; az[i][2]=0.f; az[i][3]=0.f; }

    int fs[3] = {f0, f1, f2};
#pragma unroll
    for (int ff = 0; ff < 3; ++ff) {
        int fb = fs[ff];
#pragma unroll
        for (int j = 0; j < 4; ++j) {
            float xv = (j < 2) ? rlane(xa, j * 18 + fb) : rlane(xb, (j - 2) * 18 + fb);
#pragma unroll
            for (int i = 0; i < 4; ++i) az[i][j] = fmaf(xv, wk1[ff][i], az[i][j]);
        }
    }
#pragma unroll
    for (int kl = 0; kl < 16; ++kl) {
#pragma unroll
        for (int j = 0; j < 4; ++j) {
            float hv = rlane(hdj[j], kl);
#pragma unroll
            for (int i = 0; i < 4; ++i) az[i][j] = fmaf(hv, wzr[kl][i], az[i][j]);
        }
    }
#pragma unroll
    for (int i = 0; i < 4; ++i)
        p1[w * 256 + lane + 64 * i] = make_float4(az[i][0], az[i][1], az[i][2], az[i][3]);
    __syncthreads();                                   // A

    // ---- reduce1 (threads 0..255): z -> zbuf, u = r*h -> ubuf ----
    if (tid < 256) {
        int c = tid;
        float4 s = p1[c];
#pragma unroll
        for (int ww = 1; ww < 8; ++ww) {
            float4 q = p1[ww * 256 + c];
            s.x += q.x; s.y += q.y; s.z += q.z; s.w += q.w;
        }
        s.x += breg; s.y += breg; s.z += breg; s.w += breg;
        if (c < 128) {
            zbuf[c] = make_float4(hsig(s.x), hsig(s.y), hsig(s.z), hsig(s.w));
        } else {
            int cc = c - 128;
            float4 ho = hlds[cc];
            ubuf[cc] = make_float4(hsig(s.x) * ho.x, hsig(s.y) * ho.y,
                                   hsig(s.z) * ho.z, hsig(s.w) * ho.w);
        }
    }
    __syncthreads();                                   // B

    // ---- stage 2: partials of [x@K2 + u@Rh] over this wave's k/f slice ----
    float4 ud4 = ubuf[w * 16 + l15];
    float udj[4] = {ud4.x, ud4.y, ud4.z, ud4.w};
    float p[2][4];
#pragma unroll
    for (int i = 0; i < 2; ++i) { p[i][0]=0.f; p[i][1]=0.f; p[i][2]=0.f; p[i][3]=0.f; }
#pragma unroll
    for (int ff = 0; ff < 3; ++ff) {
        int fb = fs[ff];
#pragma unroll
        for (int j = 0; j < 4; ++j) {
            float xv = (j < 2) ? rlane(xa, j * 18 + fb) : rlane(xb, (j - 2) * 18 + fb);
#pragma unroll
            for (int i = 0; i < 2; ++i) p[i][j] = fmaf(xv, wk2[ff][i], p[i][j]);
        }
    }
#pragma unroll
    for (int kl = 0; kl < 16; ++kl) {
#pragma unroll
        for (int j = 0; j < 4; ++j) {
            float uv = rlane(udj[j], kl);
#pragma unroll
            for (int i = 0; i < 2; ++i) p[i][j] = fmaf(uv, wh[kl][i], p[i][j]);
        }
    }
    p2[w * 128 + lane]      = make_float4(p[0][0], p[0][1], p[0][2], p[0][3]);
    p2[w * 128 + lane + 64] = make_float4(p[1][0], p[1][1], p[1][2], p[1][3]);
    __syncthreads();                                   // C

    // ---- reduce2 + finish (threads 0..127): h_new -> hlds ----
    if (tid < 128) {
        int c = tid;
        float4 s = p2[c];
#pragma unroll
        for (int ww = 1; ww < 8; ++ww) {
            float4 q = p2[ww * 128 + c];
            s.x += q.x; s.y += q.y; s.z += q.z; s.w += q.w;
        }
        float hh0 = tanhf(s.x + breg2), hh1 = tanhf(s.y + breg2);
        float hh2 = tanhf(s.z + breg2), hh3 = tanhf(s.w + breg2);
        float4 z = zbuf[c], ho = hlds[c];
        float n0 = fmaf(z.x, ho.x - hh0, hh0);
        float n1 = fmaf(z.y, ho.y - hh1, hh1);
        float n2 = fmaf(z.z, ho.z - hh2, hh2);
        float n3 = fmaf(z.w, ho.w - hh3, hh3);
        if (MASK) {
            if (act.x < 0) n0 = ho.x;
            if (act.y < 0) n1 = ho.y;
            if (act.z < 0) n2 = ho.z;
            if (act.w < 0) n3 = ho.w;
        }
        hlds[c] = make_float4(n0, n1, n2, n3);
    }
    __syncthreads();                                   // D
}

// ---------------------------------------------------------------------------
// weight preload shared by both kernels
// ---------------------------------------------------------------------------
#define LOAD_WEIGHTS                                                         \
    float wzr[16][4], wh[16][2], wk1[3][4], wk2[3][2];                       \
    _Pragma("unroll")                                                        \
    for (int kl = 0; kl < 16; ++kl) {                                        \
        int row = (w * 16 + kl) * 384;                                       \
        _Pragma("unroll")                                                    \
        for (int i = 0; i < 4; ++i) wzr[kl][i] = rk[row + lane + 64 * i];    \
        _Pragma("unroll")                                                    \
        for (int i = 0; i < 2; ++i) wh[kl][i] = rk[row + 256 + lane + 64*i]; \
    }                                                                        \
    int f0 = 2 * w, f1 = 2 * w + 1, f2 = (w < 2) ? 16 + w : 0;               \
    {                                                                        \
        int r0 = f0 * 384, r1 = f1 * 384, r2 = f2 * 384;                     \
        _Pragma("unroll")                                                    \
        for (int i = 0; i < 4; ++i) {                                        \
            wk1[0][i] = ker[r0 + lane + 64 * i];                             \
            wk1[1][i] = ker[r1 + lane + 64 * i];                             \
            wk1[2][i] = (w < 2) ? ker[r2 + lane + 64 * i] : 0.0f;            \
        }                                                                    \
        _Pragma("unroll")                                                    \
        for (int i = 0; i < 2; ++i) {                                        \
            wk2[0][i] = ker[r0 + 256 + lane + 64 * i];                       \
            wk2[1][i] = ker[r1 + 256 + lane + 64 * i];                       \
            wk2[2][i] = (w < 2) ? ker[r2 + 256 + lane + 64 * i] : 0.0f;      \
        }                                                                    \
    }                                                                        \
    float breg  = (tid < 256) ? bias[tid] : 0.0f;                            \
    float breg2 = (tid < 128) ? bias[256 + tid] : 0.0f;

// ---------------------------------------------------------------------------
// K2: 250 wgs x 512 threads; 4 chains/wg; t = 0..198
// ---------------------------------------------------------------------------
__global__ __launch_bounds__(512, 2)
void k_scan(const float* __restrict__ in,  const float* __restrict__ ker,
            const float* __restrict__ rk,  const float* __restrict__ bias,
            const float* __restrict__ sh0, const int* __restrict__ win,
            float* __restrict__ sfinal)
{
    const int tid  = threadIdx.x;
    const int bx   = blockIdx.x;
    const int w    = tid >> 6;
    const int lane = tid & 63;
    const int l15  = lane & 15;

    __shared__ __align__(16) float4 hlds[Uz], ubuf[Uz], zbuf[Uz];
    __shared__ __align__(16) float4 p1[8 * 256];
    __shared__ __align__(16) float4 p2[8 * 128];

    LOAD_WEIGHTS

    ((float*)hlds)[tid] = sh0[(bx * 4 + (tid & 3)) * Uz + (tid >> 2)];

    const int4* winp = (const int4*)win;               // [Tz][NWG]
    int4 wv_cur = winp[bx];
    int4 wv_nxt = winp[NWG + bx];

    auto ldx = [&](int4 wv, int t, int jb) -> float {
        if (lane >= 36) return 0.0f;
        int j = lane / 18, f = lane - j * 18;
        int jj = jb + j;
        int b = (jj == 0) ? wv.x : (jj == 1) ? wv.y : (jj == 2) ? wv.z : wv.w;
        if (b < 0) return 0.0f;
        return in[((size_t)b * Tz + t) * Fz + f];
    };
    float xa = ldx(wv_cur, 0, 0), xb = ldx(wv_cur, 0, 2);
    __syncthreads();

    for (int t = 0; t < Tz - 1; ++t) {
        int tf = (t + 2 < Tz) ? t + 2 : Tz - 1;
        int4  wv_fut = winp[tf * NWG + bx];
        float xaN = ldx(wv_nxt, t + 1, 0);             // prefetch x(t+1)
        float xbN = ldx(wv_nxt, t + 1, 2);

        gstep<true>(tid, w, lane, l15, wzr, wh, wk1, wk2, f0, f1, f2,
                    breg, breg2, hlds, ubuf, zbuf, p1, p2, xa, xb, wv_cur);

        xa = xaN; xb = xbN; wv_cur = wv_nxt; wv_nxt = wv_fut;
    }

    sfinal[bx * 512 + tid] = ((float*)hlds)[tid];
}

// ---------------------------------------------------------------------------
// K3: final step t=199 for all 4096 rows + fused MLP head
// 256 wgs x 512 threads, 4 iterations of 4 rows
// ---------------------------------------------------------------------------
__global__ __launch_bounds__(512, 2)
void k_final(const float* __restrict__ in,  const float* __restrict__ ker,
             const float* __restrict__ rk,  const float* __restrict__ bias,
             const float* __restrict__ sfinal,
             const float* __restrict__ w1,  const float* __restrict__ b1,
             const float* __restrict__ w2,  const float* __restrict__ b2,
             float* __restrict__ out)
{
    const int tid  = threadIdx.x;
    const int w    = tid >> 6;
    const int lane = tid & 63;
    const int l15  = lane & 15;

    __shared__ __align__(16) float4 hlds[Uz], ubuf[Uz], zbuf[Uz];
    __shared__ __align__(16) float4 p1[8 * 256];
    __shared__ __align__(16) float4 p2[8 * 128];

    LOAD_WEIGHTS

    for (int it = 0; it < 4; ++it) {
        int bbase = blockIdx.x * 16 + it * 4;
        {   // gather h = sfinal[id]; tid -> (chain j = tid&3, col c = tid>>2)
            int j  = tid & 3, c = tid >> 2;
            int id = (int)in[((size_t)(bbase + j) * Tz + (Tz - 1)) * Fz];
            id = min(max(id, 0), NIDS - 1);
            ((float*)hlds)[tid] = sfinal[((id >> 2) * Uz + c) * 4 + (id & 3)];
        }
        float xa = 0.0f, xb = 0.0f;
        if (lane < 36) {
            int j = lane / 18, f = lane - j * 18;
            xa = in[((size_t)(bbase + j)     * Tz + (Tz - 1)) * Fz + f];
            xb = in[((size_t)(bbase + 2 + j) * Tz + (Tz - 1)) * Fz + f];
        }
        __syncthreads();

        gstep<false>(tid, w, lane, l15, wzr, wh, wk1, wk2, f0, f1, f2,
                     breg, breg2, hlds, ubuf, zbuf, p1, p2, xa, xb,
                     make_int4(0, 0, 0, 0));

        // MLP head: wave j = tid>>6 (<4) handles row j; lane = hidden unit
        if (tid < 256) {
            int j  = tid >> 6, un = tid & 63;
            float dacc = b1[un];
#pragma unroll
            for (int k = 0; k < Uz; ++k)
                dacc = fmaf(((const float*)hlds)[k * 4 + j], w1[k * 64 + un], dacc);
            float v = fmaxf(dacc, 0.0f) * w2[un];
#pragma unroll
            for (int off = 32; off > 0; off >>= 1) v += __shfl_xor(v, off, 64);
            if (un == 0)
                out[bbase + j] = 1.0f / (1.0f + expf(-(v + b2[0])));
        }
        __syncthreads();
    }
}

// ---------------------------------------------------------------------------
extern "C" void kernel_launch(void* const* d_in, const int* in_sizes, int n_in,
                              void* d_out, int out_size, void* d_ws, size_t ws_size,
                              hipStream_t stream) {
    const float* in   = (const float*)d_in[0];
    const float* ker  = (const float*)d_in[1];
    const float* rk   = (const float*)d_in[2];
    const float* bias = (const float*)d_in[3];
    const float* sh0  = (const float*)d_in[4];
    const float* w1   = (const float*)d_in[5];
    const float* b1   = (const float*)d_in[6];
    const float* w2   = (const float*)d_in[7];
    const float* b2   = (const float*)d_in[8];
    float* out = (float*)d_out;

    int*   win    = (int*)d_ws;                                          // [Tz][NIDS]
    float* sfinal = (float*)((char*)d_ws + (size_t)Tz * NIDS * sizeof(int));

    hipMemsetAsync(win, 0xFF, (size_t)Tz * NIDS * sizeof(int), stream);  // -1

    hipLaunchKernelGGL(k_winner, dim3((Bz * Tz + 255) / 256), dim3(256), 0, stream,
                       in, win);
    hipLaunchKernelGGL(k_scan, dim3(NWG), dim3(512), 0, stream,
                       in, ker, rk, bias, sh0, win, sfinal);
    hipLaunchKernelGGL(k_final, dim3(Bz / 16), dim3(512), 0, stream,
                       in, ker, rk, bias, sfinal, w1, b1, w2, b2, out);
}